// Round 8
// baseline (84.240 us; speedup 1.0000x reference)
//
#include <hip/hip_runtime.h>

typedef float f32x4 __attribute__((ext_vector_type(4)));
typedef __bf16 bf16x8 __attribute__((ext_vector_type(8)));
typedef int i32x4 __attribute__((ext_vector_type(4)));
typedef unsigned short u16;
typedef unsigned int u32;

#define ALPHA 0.2f
#define LOG2E 1.4426950408889634f

__device__ __forceinline__ u16 f2bf(float x) {
    u32 u = __float_as_uint(x);
    u += 0x7FFFu + ((u >> 16) & 1u);   // RNE; inputs finite
    return (u16)(u >> 16);
}

// ---------------------------------------------------------------------------
// K1: Wh = h @ W^T (fp32 register-tiled), fused e_i/e_j, bf16 Wh^T store.
// 256 blocks x 256 thr. (verified rounds 1-7, unchanged)
// ---------------------------------------------------------------------------
__global__ __launch_bounds__(256) void k_wh(
    const float* __restrict__ hsrc, const float* __restrict__ Wsrc,
    const float* __restrict__ asrc,
    u16* __restrict__ WhbT,          // [8][64][2048] bf16 (f-major, m contiguous)
    float* __restrict__ ei, float* __restrict__ ej)
{
    __shared__ float Wl[64][68];
    __shared__ float hl[64][68];
    __shared__ __align__(16) u16 tl[4096];

    const int tid = threadIdx.x;
    const int tx = tid & 15, ty = tid >> 4;
    const int R0 = blockIdx.x * 64;

    float acc[4][4] = {};

    for (int kc = 0; kc < 4; ++kc) {
        const int k0 = kc * 64;
        __syncthreads();
        #pragma unroll
        for (int p = 0; p < 4; ++p) {
            int idx = p * 1024 + tid * 4;
            int row = idx >> 6, k = idx & 63;
            float4 wv4 = *reinterpret_cast<const float4*>(&Wsrc[row * 256 + k0 + k]);
            Wl[k + 0][row] = wv4.x; Wl[k + 1][row] = wv4.y;
            Wl[k + 2][row] = wv4.z; Wl[k + 3][row] = wv4.w;
            float4 hv4 = *reinterpret_cast<const float4*>(&hsrc[(size_t)(R0 + row) * 256 + k0 + k]);
            hl[k + 0][row] = hv4.x; hl[k + 1][row] = hv4.y;
            hl[k + 2][row] = hv4.z; hl[k + 3][row] = hv4.w;
        }
        __syncthreads();
        #pragma unroll 4
        for (int k = 0; k < 64; ++k) {
            float4 hv = *reinterpret_cast<const float4*>(&hl[k][4 * ty]);
            float4 wv = *reinterpret_cast<const float4*>(&Wl[k][4 * tx]);
            float hr[4] = {hv.x, hv.y, hv.z, hv.w};
            float wc[4] = {wv.x, wv.y, wv.z, wv.w};
            #pragma unroll
            for (int i = 0; i < 4; ++i)
                #pragma unroll
                for (int j = 0; j < 4; ++j)
                    acc[i][j] = fmaf(hr[i], wc[j], acc[i][j]);
        }
    }

    float4 av_i = *reinterpret_cast<const float4*>(&asrc[4 * tx]);
    float4 av_j = *reinterpret_cast<const float4*>(&asrc[64 + 4 * tx]);
    #pragma unroll
    for (int i = 0; i < 4; ++i) {
        float pi = acc[i][0]*av_i.x + acc[i][1]*av_i.y + acc[i][2]*av_i.z + acc[i][3]*av_i.w;
        float pj = acc[i][0]*av_j.x + acc[i][1]*av_j.y + acc[i][2]*av_j.z + acc[i][3]*av_j.w;
        #pragma unroll
        for (int off = 1; off < 16; off <<= 1) {
            pi += __shfl_xor(pi, off, 64);
            pj += __shfl_xor(pj, off, 64);
        }
        if (tx == 0) {
            ei[R0 + 4 * ty + i] = pi;
            ej[R0 + 4 * ty + i] = pj;
        }
    }

    #pragma unroll
    for (int i = 0; i < 4; ++i)
        #pragma unroll
        for (int j = 0; j < 4; ++j) {
            int row = 4 * tx + j;    // o
            int col = 4 * ty + i;    // r
            tl[(row * 64 + col) ^ ((row & 7) << 3)] = f2bf(acc[i][j]);
        }
    __syncthreads();
    {
        const int b = blockIdx.x >> 5;
        const int nloc = (blockIdx.x & 31) * 64;
        const int o = tid >> 2, rg = tid & 3;
        #pragma unroll
        for (int c = 0; c < 2; ++c) {
            int u = (o * 64 + rg * 16 + 8 * c) ^ ((o & 7) << 3);
            int4 v = *reinterpret_cast<const int4*>(&tl[u]);
            *reinterpret_cast<int4*>(&WhbT[(size_t)(b * 64 + o) * 2048 + nloc + rg * 16 + 8 * c]) = v;
        }
    }
}

// ---------------------------------------------------------------------------
// K2: fused attention, stream-then-compute per wave, 4 waves/SIMD.
// 1024 blocks (8b x 128 16-row tiles, XCD-contig) x 256 thr (4 m-quarter waves).
// Phase A: wave streams its 16rows x 512m adj slice ONCE (rolling 8-pair
// register prefetch, nontemporal) and packs to 4 VGPRs of bits (2 VALU/int).
// Phase B: 16 MFMA STEPs; adj from bit-regs, ej*log2e from private LDS slice
// (no barrier), Wh B-frags from hot L2 with 2-STEP prefetch, denominator via
// 5th MFMA vs ones-fragment. Quarters combine in LDS; direct out write.
// Mj loads fully consumed BEFORE phase A so nothing young waits behind the
// adj queue (vmcnt counts in order).
// ---------------------------------------------------------------------------
__global__ __launch_bounds__(256, 4) void k_attn(
    const int* __restrict__ adj, const u16* __restrict__ WhbT,
    const float* __restrict__ ei_g, const float* __restrict__ ej_g,
    float* __restrict__ out)
{
    __shared__ float ejl[4][520];        // per-wave ej slice (scaled by log2e)
    __shared__ float comb[3][64][21];    // quarter-combine buffer

    const int tid  = threadIdx.x;
    const int lane = tid & 63;
    const int mq   = tid >> 6;                        // m-quarter 0..3
    const int lb   = (int)(blockIdx.x & 7) * 128 + (int)(blockIdx.x >> 3);
    const int b    = lb >> 7;                         // batch (one per XCD)
    const int n0   = (lb & 127) * 16;                 // 16-row tile base
    const int r    = lane & 15;                       // A-frag row / B-frag f
    const int ks   = lane >> 4;                       // k-slot group

    // ---- Mj = max_m e_j[b,m]  (consumed fully before phase A issues) ----
    float mj = -1e30f;
    #pragma unroll
    for (int i = 0; i < 8; ++i) {
        float4 v = *reinterpret_cast<const float4*>(&ej_g[b * 2048 + (i * 64 + lane) * 4]);
        mj = fmaxf(mj, fmaxf(fmaxf(v.x, v.y), fmaxf(v.z, v.w)));
    }
    #pragma unroll
    for (int off = 1; off < 64; off <<= 1) mj = fmaxf(mj, __shfl_xor(mj, off, 64));

    const float eiv2 = ei_g[b * 2048 + n0 + r] * LOG2E;
    const float xM2  = eiv2 + mj * LOG2E;
    const float M2   = fmaxf(xM2, ALPHA * xM2);   // log2-domain row upper bound

    // ---- stage this wave's ej slice (512 floats, own-wave only: no barrier) ----
    {
        float4 v0 = *reinterpret_cast<const float4*>(&ej_g[b * 2048 + mq * 512 + lane * 8]);
        float4 v1 = *reinterpret_cast<const float4*>(&ej_g[b * 2048 + mq * 512 + lane * 8 + 4]);
        v0.x *= LOG2E; v0.y *= LOG2E; v0.z *= LOG2E; v0.w *= LOG2E;
        v1.x *= LOG2E; v1.y *= LOG2E; v1.z *= LOG2E; v1.w *= LOG2E;
        *reinterpret_cast<float4*>(&ejl[mq][lane * 8])     = v0;
        *reinterpret_cast<float4*>(&ejl[mq][lane * 8 + 4]) = v1;
    }

    // ---- phase A: stream adj -> 4 bit-VGPRs (rolling 8-pair prefetch) ----
    const int* adjp = adj + (size_t)(b * 2048 + n0 + r) * 2048 + mq * 512 + ks * 8;
    u32 bits0 = 0, bits1 = 0, bits2 = 0, bits3 = 0;
    i32x4 Aq0, Aq1, Bq0, Bq1, Cq0, Cq1, Dq0, Dq1;
    i32x4 Eq0, Eq1, Fq0, Fq1, Gq0, Gq1, Hq0, Hq1;

#define LA(t, x0, x1) { \
    x0 = __builtin_nontemporal_load(reinterpret_cast<const i32x4*>(adjp + (t) * 32)); \
    x1 = __builtin_nontemporal_load(reinterpret_cast<const i32x4*>(adjp + (t) * 32 + 4)); }
#define PK(x0, x1, W, sh) { u32 m_ = 0; \
    m_ |= (x0[0] != 0) ? 1u   : 0u; m_ |= (x0[1] != 0) ? 2u   : 0u; \
    m_ |= (x0[2] != 0) ? 4u   : 0u; m_ |= (x0[3] != 0) ? 8u   : 0u; \
    m_ |= (x1[0] != 0) ? 16u  : 0u; m_ |= (x1[1] != 0) ? 32u  : 0u; \
    m_ |= (x1[2] != 0) ? 64u  : 0u; m_ |= (x1[3] != 0) ? 128u : 0u; \
    W |= m_ << (sh); }

    LA(0, Aq0, Aq1); LA(1, Bq0, Bq1); LA(2, Cq0, Cq1); LA(3, Dq0, Dq1);
    LA(4, Eq0, Eq1); LA(5, Fq0, Fq1); LA(6, Gq0, Gq1); LA(7, Hq0, Hq1);

    PK(Aq0, Aq1, bits0, 0);  LA(8,  Aq0, Aq1);
    PK(Bq0, Bq1, bits0, 8);  LA(9,  Bq0, Bq1);
    PK(Cq0, Cq1, bits0, 16); LA(10, Cq0, Cq1);
    PK(Dq0, Dq1, bits0, 24); LA(11, Dq0, Dq1);
    PK(Eq0, Eq1, bits1, 0);  LA(12, Eq0, Eq1);
    PK(Fq0, Fq1, bits1, 8);  LA(13, Fq0, Fq1);
    PK(Gq0, Gq1, bits1, 16); LA(14, Gq0, Gq1);
    PK(Hq0, Hq1, bits1, 24); LA(15, Hq0, Hq1);
    PK(Aq0, Aq1, bits2, 0);
    PK(Bq0, Bq1, bits2, 8);
    PK(Cq0, Cq1, bits2, 16);
    PK(Dq0, Dq1, bits2, 24);
    PK(Eq0, Eq1, bits3, 0);
    PK(Fq0, Fq1, bits3, 8);
    PK(Gq0, Gq1, bits3, 16);
    PK(Hq0, Hq1, bits3, 24);
#undef PK
#undef LA

    // ---- phase B: 16 MFMA STEPs, Wh from L2 (2-STEP prefetch) ----
    bf16x8 bones;
    {
        const float o = (r == 0) ? 1.0f : 0.0f;
        #pragma unroll
        for (int j = 0; j < 8; ++j) bones[j] = (__bf16)o;
    }

    const u16*   whp = WhbT + (size_t)(b * 64 + r) * 2048 + mq * 512 + ks * 8;
    const float* eb  = &ejl[mq][ks * 8];

    bf16x8 Aw0, Aw1, Aw2, Aw3, Bw0, Bw1, Bw2, Bw3;
#define LDW(t, w0, w1, w2, w3) { const u16* pp = whp + (t) * 32; \
    w0 = *reinterpret_cast<const bf16x8*>(pp); \
    w1 = *reinterpret_cast<const bf16x8*>(pp + 32768); \
    w2 = *reinterpret_cast<const bf16x8*>(pp + 65536); \
    w3 = *reinterpret_cast<const bf16x8*>(pp + 98304); }

#define PVAL(mk, ev, dst) { \
    float x_ = eiv2 + (ev); \
    float lr_ = fmaxf(x_, ALPHA * x_); \
    float p_ = exp2f(lr_ - M2); \
    dst = (__bf16)(((mk) != 0u) ? p_ : 0.0f); }

    f32x4 acc0 = {}, acc1 = {}, acc2 = {}, acc3 = {}, acc4 = {};

#define STEP(t, BW, w0, w1, w2, w3) { \
    const u32 by_ = (BW) >> (((t) & 3) * 8); \
    float4 e0 = *reinterpret_cast<const float4*>(eb + (t) * 32); \
    float4 e1 = *reinterpret_cast<const float4*>(eb + (t) * 32 + 4); \
    bf16x8 af; \
    PVAL(by_ & 1u,   e0.x, af[0]); PVAL(by_ & 2u,   e0.y, af[1]); \
    PVAL(by_ & 4u,   e0.z, af[2]); PVAL(by_ & 8u,   e0.w, af[3]); \
    PVAL(by_ & 16u,  e1.x, af[4]); PVAL(by_ & 32u,  e1.y, af[5]); \
    PVAL(by_ & 64u,  e1.z, af[6]); PVAL(by_ & 128u, e1.w, af[7]); \
    acc0 = __builtin_amdgcn_mfma_f32_16x16x32_bf16(af, w0, acc0, 0, 0, 0); \
    acc1 = __builtin_amdgcn_mfma_f32_16x16x32_bf16(af, w1, acc1, 0, 0, 0); \
    acc2 = __builtin_amdgcn_mfma_f32_16x16x32_bf16(af, w2, acc2, 0, 0, 0); \
    acc3 = __builtin_amdgcn_mfma_f32_16x16x32_bf16(af, w3, acc3, 0, 0, 0); \
    acc4 = __builtin_amdgcn_mfma_f32_16x16x32_bf16(af, bones, acc4, 0, 0, 0); }

    LDW(0, Aw0, Aw1, Aw2, Aw3);
    LDW(1, Bw0, Bw1, Bw2, Bw3);
    STEP(0,  bits0, Aw0, Aw1, Aw2, Aw3); LDW(2,  Aw0, Aw1, Aw2, Aw3);
    STEP(1,  bits0, Bw0, Bw1, Bw2, Bw3); LDW(3,  Bw0, Bw1, Bw2, Bw3);
    STEP(2,  bits0, Aw0, Aw1, Aw2, Aw3); LDW(4,  Aw0, Aw1, Aw2, Aw3);
    STEP(3,  bits0, Bw0, Bw1, Bw2, Bw3); LDW(5,  Bw0, Bw1, Bw2, Bw3);
    STEP(4,  bits1, Aw0, Aw1, Aw2, Aw3); LDW(6,  Aw0, Aw1, Aw2, Aw3);
    STEP(5,  bits1, Bw0, Bw1, Bw2, Bw3); LDW(7,  Bw0, Bw1, Bw2, Bw3);
    STEP(6,  bits1, Aw0, Aw1, Aw2, Aw3); LDW(8,  Aw0, Aw1, Aw2, Aw3);
    STEP(7,  bits1, Bw0, Bw1, Bw2, Bw3); LDW(9,  Bw0, Bw1, Bw2, Bw3);
    STEP(8,  bits2, Aw0, Aw1, Aw2, Aw3); LDW(10, Aw0, Aw1, Aw2, Aw3);
    STEP(9,  bits2, Bw0, Bw1, Bw2, Bw3); LDW(11, Bw0, Bw1, Bw2, Bw3);
    STEP(10, bits2, Aw0, Aw1, Aw2, Aw3); LDW(12, Aw0, Aw1, Aw2, Aw3);
    STEP(11, bits2, Bw0, Bw1, Bw2, Bw3); LDW(13, Bw0, Bw1, Bw2, Bw3);
    STEP(12, bits3, Aw0, Aw1, Aw2, Aw3); LDW(14, Aw0, Aw1, Aw2, Aw3);
    STEP(13, bits3, Bw0, Bw1, Bw2, Bw3); LDW(15, Bw0, Bw1, Bw2, Bw3);
    STEP(14, bits3, Aw0, Aw1, Aw2, Aw3);
    STEP(15, bits3, Bw0, Bw1, Bw2, Bw3);
#undef STEP
#undef PVAL
#undef LDW

    // ---- combine quarters (single barrier) + normalize + direct out ----
    if (mq != 0) {
        #pragma unroll
        for (int q = 0; q < 4; ++q) {
            comb[mq - 1][lane][q]      = acc0[q];
            comb[mq - 1][lane][4 + q]  = acc1[q];
            comb[mq - 1][lane][8 + q]  = acc2[q];
            comb[mq - 1][lane][12 + q] = acc3[q];
            comb[mq - 1][lane][16 + q] = acc4[q];
        }
    }
    __syncthreads();
    if (mq == 0) {
        #pragma unroll
        for (int w = 0; w < 3; ++w) {
            #pragma unroll
            for (int q = 0; q < 4; ++q) {
                acc0[q] += comb[w][lane][q];
                acc1[q] += comb[w][lane][4 + q];
                acc2[q] += comb[w][lane][8 + q];
                acc3[q] += comb[w][lane][12 + q];
                acc4[q] += comb[w][lane][16 + q];
            }
        }
        #pragma unroll
        for (int q = 0; q < 4; ++q) {
            float d   = __shfl(acc4[q], lane & 48, 64);   // den in r==0 lanes
            float inv = (d > 0.0f) ? 1.0f / d : 0.0f;     // all-masked row -> 0
            const int n = n0 + ks * 4 + q;
            float* op = out + (size_t)(b * 2048 + n) * 64 + r;
            op[0]  = acc0[q] * inv;
            op[16] = acc1[q] * inv;
            op[32] = acc2[q] * inv;
            op[48] = acc3[q] * inv;
        }
    }
}

// ---------------------------------------------------------------------------
extern "C" void kernel_launch(void* const* d_in, const int* in_sizes, int n_in,
                              void* d_out, int out_size, void* d_ws, size_t ws_size,
                              hipStream_t stream)
{
    const float* h   = (const float*)d_in[0];   // [8,2048,256]
    const int*   adj = (const int*)d_in[1];     // [8,2048,2048]
    const float* W   = (const float*)d_in[2];   // [64,256]
    const float* a   = (const float*)d_in[3];   // [1,128]
    float* out = (float*)d_out;                  // [8,2048,64]

    u16*   WhbT = (u16*)d_ws;                               // 2 MB
    float* ei   = (float*)((char*)d_ws + 2 * 1024 * 1024);  // 64 KB
    float* ej   = ei + 16384;                               // 64 KB

    k_wh  <<<dim3(256),  dim3(256), 0, stream>>>(h, W, a, WhbT, ei, ej);
    k_attn<<<dim3(1024), dim3(256), 0, stream>>>(adj, WhbT, ei, ej, out);
}

// Round 9
// 73.852 us; speedup vs baseline: 1.1407x; 1.1407x over previous
//
#include <hip/hip_runtime.h>

typedef float f32x4 __attribute__((ext_vector_type(4)));
typedef __bf16 bf16x8 __attribute__((ext_vector_type(8)));
typedef int i32x4 __attribute__((ext_vector_type(4)));
typedef unsigned short u16;
typedef unsigned int u32;

#define ALPHA 0.2f
#define LOG2E 1.4426950408889634f

__device__ __forceinline__ u16 f2bf(float x) {
    u32 u = __float_as_uint(x);
    u += 0x7FFFu + ((u >> 16) & 1u);   // RNE; inputs finite
    return (u16)(u >> 16);
}

// ---------------------------------------------------------------------------
// K1: Wh = h @ W^T (fp32 register-tiled), fused e_i/e_j, bf16 Wh^T store.
// 256 blocks x 256 thr. (verified rounds 1-8, unchanged)
// ---------------------------------------------------------------------------
__global__ __launch_bounds__(256) void k_wh(
    const float* __restrict__ hsrc, const float* __restrict__ Wsrc,
    const float* __restrict__ asrc,
    u16* __restrict__ WhbT,          // [8][64][2048] bf16 (f-major, m contiguous)
    float* __restrict__ ei, float* __restrict__ ej)
{
    __shared__ float Wl[64][68];
    __shared__ float hl[64][68];
    __shared__ __align__(16) u16 tl[4096];

    const int tid = threadIdx.x;
    const int tx = tid & 15, ty = tid >> 4;
    const int R0 = blockIdx.x * 64;

    float acc[4][4] = {};

    for (int kc = 0; kc < 4; ++kc) {
        const int k0 = kc * 64;
        __syncthreads();
        #pragma unroll
        for (int p = 0; p < 4; ++p) {
            int idx = p * 1024 + tid * 4;
            int row = idx >> 6, k = idx & 63;
            float4 wv4 = *reinterpret_cast<const float4*>(&Wsrc[row * 256 + k0 + k]);
            Wl[k + 0][row] = wv4.x; Wl[k + 1][row] = wv4.y;
            Wl[k + 2][row] = wv4.z; Wl[k + 3][row] = wv4.w;
            float4 hv4 = *reinterpret_cast<const float4*>(&hsrc[(size_t)(R0 + row) * 256 + k0 + k]);
            hl[k + 0][row] = hv4.x; hl[k + 1][row] = hv4.y;
            hl[k + 2][row] = hv4.z; hl[k + 3][row] = hv4.w;
        }
        __syncthreads();
        #pragma unroll 4
        for (int k = 0; k < 64; ++k) {
            float4 hv = *reinterpret_cast<const float4*>(&hl[k][4 * ty]);
            float4 wv = *reinterpret_cast<const float4*>(&Wl[k][4 * tx]);
            float hr[4] = {hv.x, hv.y, hv.z, hv.w};
            float wc[4] = {wv.x, wv.y, wv.z, wv.w};
            #pragma unroll
            for (int i = 0; i < 4; ++i)
                #pragma unroll
                for (int j = 0; j < 4; ++j)
                    acc[i][j] = fmaf(hr[i], wc[j], acc[i][j]);
        }
    }

    float4 av_i = *reinterpret_cast<const float4*>(&asrc[4 * tx]);
    float4 av_j = *reinterpret_cast<const float4*>(&asrc[64 + 4 * tx]);
    #pragma unroll
    for (int i = 0; i < 4; ++i) {
        float pi = acc[i][0]*av_i.x + acc[i][1]*av_i.y + acc[i][2]*av_i.z + acc[i][3]*av_i.w;
        float pj = acc[i][0]*av_j.x + acc[i][1]*av_j.y + acc[i][2]*av_j.z + acc[i][3]*av_j.w;
        #pragma unroll
        for (int off = 1; off < 16; off <<= 1) {
            pi += __shfl_xor(pi, off, 64);
            pj += __shfl_xor(pj, off, 64);
        }
        if (tx == 0) {
            ei[R0 + 4 * ty + i] = pi;
            ej[R0 + 4 * ty + i] = pj;
        }
    }

    #pragma unroll
    for (int i = 0; i < 4; ++i)
        #pragma unroll
        for (int j = 0; j < 4; ++j) {
            int row = 4 * tx + j;    // o
            int col = 4 * ty + i;    // r
            tl[(row * 64 + col) ^ ((row & 7) << 3)] = f2bf(acc[i][j]);
        }
    __syncthreads();
    {
        const int b = blockIdx.x >> 5;
        const int nloc = (blockIdx.x & 31) * 64;
        const int o = tid >> 2, rg = tid & 3;
        #pragma unroll
        for (int c = 0; c < 2; ++c) {
            int u = (o * 64 + rg * 16 + 8 * c) ^ ((o & 7) << 3);
            int4 v = *reinterpret_cast<const int4*>(&tl[u]);
            *reinterpret_cast<int4*>(&WhbT[(size_t)(b * 64 + o) * 2048 + nloc + rg * 16 + 8 * c]) = v;
        }
    }
}

// ---------------------------------------------------------------------------
// K2: fused attention. 1024 blocks (8b x 128 16-row tiles, XCD-contig) x 256.
// Phase 1: block streams its 16x2048 adj tile SEQUENTIALLY (thread t owns
// cols 8t..8t+7; block reads one full 8KB row per iter -> DRAM-page-friendly,
// 128 KB contiguous per block), rolling 4-deep, packs to LDS byte masks
// (XOR-swizzled). One barrier. Phase 2: 4 m-quarter waves x 16 MFMA STEPs;
// masks from LDS u8, ej*log2e from LDS broadcast, Wh B-frags from L2 with
// 2-STEP ping-pong prefetch; 5th MFMA vs ones = denominator. Combine in LDS,
// write out directly.
// ---------------------------------------------------------------------------
__global__ __launch_bounds__(256) void k_attn(
    const int* __restrict__ adj, const u16* __restrict__ WhbT,
    const float* __restrict__ ei_g, const float* __restrict__ ej_g,
    float* __restrict__ out)
{
    __shared__ char msk[16 * 256];       // 4 KB byte masks, XOR-swizzled
    __shared__ float ejl[2048];          // 8 KB ej * log2e
    __shared__ float comb[3][64][21];    // quarter-combine buffer

    const int tid  = threadIdx.x;
    const int lane = tid & 63;
    const int mq   = tid >> 6;                        // m-quarter 0..3
    const int lb   = (int)(blockIdx.x & 7) * 128 + (int)(blockIdx.x >> 3);
    const int b    = lb >> 7;                         // batch (one per XCD)
    const int n0   = (lb & 127) * 16;                 // 16-row tile base
    const int fr   = lane & 15;                       // A-frag row / B-frag f
    const int ks   = lane >> 4;                       // k-slot group

    // ---- stage ej * log2e (full 2048, 8 KB) ----
    {
        float4 v0 = *reinterpret_cast<const float4*>(&ej_g[b * 2048 + tid * 8]);
        float4 v1 = *reinterpret_cast<const float4*>(&ej_g[b * 2048 + tid * 8 + 4]);
        v0.x *= LOG2E; v0.y *= LOG2E; v0.z *= LOG2E; v0.w *= LOG2E;
        v1.x *= LOG2E; v1.y *= LOG2E; v1.z *= LOG2E; v1.w *= LOG2E;
        *reinterpret_cast<float4*>(&ejl[tid * 8])     = v0;
        *reinterpret_cast<float4*>(&ejl[tid * 8 + 4]) = v1;
    }

    // ---- Mj = max_m e_j[b,m] (L2; consumed fully before the adj stream) ----
    float mj = -1e30f;
    #pragma unroll
    for (int i = 0; i < 8; ++i) {
        float4 v = *reinterpret_cast<const float4*>(&ej_g[b * 2048 + (i * 64 + lane) * 4]);
        mj = fmaxf(mj, fmaxf(fmaxf(v.x, v.y), fmaxf(v.z, v.w)));
    }
    #pragma unroll
    for (int off = 1; off < 64; off <<= 1) mj = fmaxf(mj, __shfl_xor(mj, off, 64));

    const float eiv2 = ei_g[b * 2048 + n0 + fr] * LOG2E;
    const float xM2  = eiv2 + mj * LOG2E;
    const float M2   = fmaxf(xM2, ALPHA * xM2);   // log2-domain row upper bound

    // ---- phase 1: sequential stream of the 16x2048 adj tile -> LDS masks ----
    const int* ap = adj + (size_t)(b * 2048 + n0) * 2048 + tid * 8;
    i32x4 q0a, q0b, q1a, q1b, q2a, q2b, q3a, q3b;

#define LDI(i, xa, xb) { \
    xa = __builtin_nontemporal_load(reinterpret_cast<const i32x4*>(ap + (i) * 2048)); \
    xb = __builtin_nontemporal_load(reinterpret_cast<const i32x4*>(ap + (i) * 2048 + 4)); }
#define PCK(i, xa, xb) { u32 m_ = 0; \
    m_ |= (xa[0] != 0) ? 1u   : 0u; m_ |= (xa[1] != 0) ? 2u   : 0u; \
    m_ |= (xa[2] != 0) ? 4u   : 0u; m_ |= (xa[3] != 0) ? 8u   : 0u; \
    m_ |= (xb[0] != 0) ? 16u  : 0u; m_ |= (xb[1] != 0) ? 32u  : 0u; \
    m_ |= (xb[2] != 0) ? 64u  : 0u; m_ |= (xb[3] != 0) ? 128u : 0u; \
    msk[(i) * 256 + (tid ^ (((i) & 15) << 4))] = (char)m_; }

    LDI(0, q0a, q0b); LDI(1, q1a, q1b); LDI(2, q2a, q2b); LDI(3, q3a, q3b);
    PCK(0,  q0a, q0b); LDI(4,  q0a, q0b);
    PCK(1,  q1a, q1b); LDI(5,  q1a, q1b);
    PCK(2,  q2a, q2b); LDI(6,  q2a, q2b);
    PCK(3,  q3a, q3b); LDI(7,  q3a, q3b);
    PCK(4,  q0a, q0b); LDI(8,  q0a, q0b);
    PCK(5,  q1a, q1b); LDI(9,  q1a, q1b);
    PCK(6,  q2a, q2b); LDI(10, q2a, q2b);
    PCK(7,  q3a, q3b); LDI(11, q3a, q3b);
    PCK(8,  q0a, q0b); LDI(12, q0a, q0b);
    PCK(9,  q1a, q1b); LDI(13, q1a, q1b);
    PCK(10, q2a, q2b); LDI(14, q2a, q2b);
    PCK(11, q3a, q3b); LDI(15, q3a, q3b);
    PCK(12, q0a, q0b);
    PCK(13, q1a, q1b);
    PCK(14, q2a, q2b);
    PCK(15, q3a, q3b);
#undef PCK
#undef LDI

    __syncthreads();   // masks + ejl visible

    // ---- phase 2: 16 MFMA STEPs over this wave's m-quarter ----
    bf16x8 bones;
    {
        const float o = (fr == 0) ? 1.0f : 0.0f;
        #pragma unroll
        for (int j = 0; j < 8; ++j) bones[j] = (__bf16)o;
    }

    const u16*   whp  = WhbT + (size_t)(b * 64 + fr) * 2048 + mq * 512 + ks * 8;
    const float* eb   = &ejl[mq * 512 + ks * 8];
    const char*  mrow = &msk[fr * 256];
    const int    mxor = (fr & 15) << 4;

    f32x4 acc0 = {}, acc1 = {}, acc2 = {}, acc3 = {}, acc4 = {};
    bf16x8 Aw0, Aw1, Aw2, Aw3, Bw0, Bw1, Bw2, Bw3;

#define LDW(t, w0, w1, w2, w3) { const u16* pp = whp + (t) * 32; \
    w0 = *reinterpret_cast<const bf16x8*>(pp); \
    w1 = *reinterpret_cast<const bf16x8*>(pp + 32768); \
    w2 = *reinterpret_cast<const bf16x8*>(pp + 65536); \
    w3 = *reinterpret_cast<const bf16x8*>(pp + 98304); }

#define PVAL(mk, ev, dst) { \
    float x_ = eiv2 + (ev); \
    float lr_ = fmaxf(x_, ALPHA * x_); \
    float p_ = exp2f(lr_ - M2); \
    dst = (__bf16)(((mk) != 0u) ? p_ : 0.0f); }

#define STEP(t, w0, w1, w2, w3) { \
    const u32 by_ = (u32)(unsigned char)mrow[(mq * 64 + (t) * 4 + ks) ^ mxor]; \
    float4 e0 = *reinterpret_cast<const float4*>(eb + (t) * 32); \
    float4 e1 = *reinterpret_cast<const float4*>(eb + (t) * 32 + 4); \
    bf16x8 af; \
    PVAL(by_ & 1u,   e0.x, af[0]); PVAL(by_ & 2u,   e0.y, af[1]); \
    PVAL(by_ & 4u,   e0.z, af[2]); PVAL(by_ & 8u,   e0.w, af[3]); \
    PVAL(by_ & 16u,  e1.x, af[4]); PVAL(by_ & 32u,  e1.y, af[5]); \
    PVAL(by_ & 64u,  e1.z, af[6]); PVAL(by_ & 128u, e1.w, af[7]); \
    acc0 = __builtin_amdgcn_mfma_f32_16x16x32_bf16(af, w0, acc0, 0, 0, 0); \
    acc1 = __builtin_amdgcn_mfma_f32_16x16x32_bf16(af, w1, acc1, 0, 0, 0); \
    acc2 = __builtin_amdgcn_mfma_f32_16x16x32_bf16(af, w2, acc2, 0, 0, 0); \
    acc3 = __builtin_amdgcn_mfma_f32_16x16x32_bf16(af, w3, acc3, 0, 0, 0); \
    acc4 = __builtin_amdgcn_mfma_f32_16x16x32_bf16(af, bones, acc4, 0, 0, 0); }

    LDW(0, Aw0, Aw1, Aw2, Aw3);
    LDW(1, Bw0, Bw1, Bw2, Bw3);
    STEP(0,  Aw0, Aw1, Aw2, Aw3); LDW(2,  Aw0, Aw1, Aw2, Aw3);
    STEP(1,  Bw0, Bw1, Bw2, Bw3); LDW(3,  Bw0, Bw1, Bw2, Bw3);
    STEP(2,  Aw0, Aw1, Aw2, Aw3); LDW(4,  Aw0, Aw1, Aw2, Aw3);
    STEP(3,  Bw0, Bw1, Bw2, Bw3); LDW(5,  Bw0, Bw1, Bw2, Bw3);
    STEP(4,  Aw0, Aw1, Aw2, Aw3); LDW(6,  Aw0, Aw1, Aw2, Aw3);
    STEP(5,  Bw0, Bw1, Bw2, Bw3); LDW(7,  Bw0, Bw1, Bw2, Bw3);
    STEP(6,  Aw0, Aw1, Aw2, Aw3); LDW(8,  Aw0, Aw1, Aw2, Aw3);
    STEP(7,  Bw0, Bw1, Bw2, Bw3); LDW(9,  Bw0, Bw1, Bw2, Bw3);
    STEP(8,  Aw0, Aw1, Aw2, Aw3); LDW(10, Aw0, Aw1, Aw2, Aw3);
    STEP(9,  Bw0, Bw1, Bw2, Bw3); LDW(11, Bw0, Bw1, Bw2, Bw3);
    STEP(10, Aw0, Aw1, Aw2, Aw3); LDW(12, Aw0, Aw1, Aw2, Aw3);
    STEP(11, Bw0, Bw1, Bw2, Bw3); LDW(13, Bw0, Bw1, Bw2, Bw3);
    STEP(12, Aw0, Aw1, Aw2, Aw3); LDW(14, Aw0, Aw1, Aw2, Aw3);
    STEP(13, Bw0, Bw1, Bw2, Bw3); LDW(15, Bw0, Bw1, Bw2, Bw3);
    STEP(14, Aw0, Aw1, Aw2, Aw3);
    STEP(15, Bw0, Bw1, Bw2, Bw3);
#undef STEP
#undef PVAL
#undef LDW

    // ---- combine quarters (single barrier) + normalize + direct out ----
    if (mq != 0) {
        #pragma unroll
        for (int q = 0; q < 4; ++q) {
            comb[mq - 1][lane][q]      = acc0[q];
            comb[mq - 1][lane][4 + q]  = acc1[q];
            comb[mq - 1][lane][8 + q]  = acc2[q];
            comb[mq - 1][lane][12 + q] = acc3[q];
            comb[mq - 1][lane][16 + q] = acc4[q];
        }
    }
    __syncthreads();
    if (mq == 0) {
        #pragma unroll
        for (int w = 0; w < 3; ++w) {
            #pragma unroll
            for (int q = 0; q < 4; ++q) {
                acc0[q] += comb[w][lane][q];
                acc1[q] += comb[w][lane][4 + q];
                acc2[q] += comb[w][lane][8 + q];
                acc3[q] += comb[w][lane][12 + q];
                acc4[q] += comb[w][lane][16 + q];
            }
        }
        #pragma unroll
        for (int q = 0; q < 4; ++q) {
            float d   = __shfl(acc4[q], lane & 48, 64);   // den in fr==0 lanes
            float inv = (d > 0.0f) ? 1.0f / d : 0.0f;     // all-masked row -> 0
            const int n = n0 + ks * 4 + q;
            float* op = out + (size_t)(b * 2048 + n) * 64 + fr;
            op[0]  = acc0[q] * inv;
            op[16] = acc1[q] * inv;
            op[32] = acc2[q] * inv;
            op[48] = acc3[q] * inv;
        }
    }
}

// ---------------------------------------------------------------------------
extern "C" void kernel_launch(void* const* d_in, const int* in_sizes, int n_in,
                              void* d_out, int out_size, void* d_ws, size_t ws_size,
                              hipStream_t stream)
{
    const float* h   = (const float*)d_in[0];   // [8,2048,256]
    const int*   adj = (const int*)d_in[1];     // [8,2048,2048]
    const float* W   = (const float*)d_in[2];   // [64,256]
    const float* a   = (const float*)d_in[3];   // [1,128]
    float* out = (float*)d_out;                  // [8,2048,64]

    u16*   WhbT = (u16*)d_ws;                               // 2 MB
    float* ei   = (float*)((char*)d_ws + 2 * 1024 * 1024);  // 64 KB
    float* ej   = ei + 16384;                               // 64 KB

    k_wh  <<<dim3(256),  dim3(256), 0, stream>>>(h, W, a, WhbT, ei, ej);
    k_attn<<<dim3(1024), dim3(256), 0, stream>>>(adj, WhbT, ei, ej, out);
}